// Round 1
// baseline (425.146 us; speedup 1.0000x reference)
//
#include <hip/hip_runtime.h>

#define D_MODEL 768
#define NHEADS  12
#define SEQ     2048
#define BATCH   4
#define FF_DIM  3072
#define NTOK    (BATCH * SEQ)

typedef short short8 __attribute__((ext_vector_type(8)));
typedef float f32x4 __attribute__((ext_vector_type(4)));
typedef unsigned short ushort4v __attribute__((ext_vector_type(4)));
typedef float float4v __attribute__((ext_vector_type(4)));

__device__ __forceinline__ short f2bf(float x) {
  unsigned u = __builtin_bit_cast(unsigned, x);
  u += 0x7fffu + ((u >> 16) & 1u);   // RNE
  return (short)(u >> 16);
}

__device__ __forceinline__ void gll16(const void* g, void* l) {
  __builtin_amdgcn_global_load_lds(
      (const __attribute__((address_space(1))) void*)g,
      (__attribute__((address_space(3))) void*)l, 16, 0, 0);
}

// ---------------- weight cast+transpose: W[K][N] f32 -> Wt[N][K] bf16 ----------------
__global__ __launch_bounds__(256) void wt_cast(const float* __restrict__ W,
                                               short* __restrict__ Wt, int K, int N) {
  __shared__ float T[64][65];
  const int t = threadIdx.x;
  const int c = t & 63, rb = t >> 6;
  const int k0 = blockIdx.y * 64, n0 = blockIdx.x * 64;
#pragma unroll
  for (int i = 0; i < 16; ++i) {
    const int r = rb * 16 + i;
    T[c][r] = W[(size_t)(k0 + r) * N + n0 + c];
  }
  __syncthreads();
#pragma unroll
  for (int j = 0; j < 16; ++j) {
    const int idx = t + j * 256;
    const int nl = idx >> 6, kl = idx & 63;
    Wt[(size_t)(n0 + nl) * K + k0 + kl] = f2bf(T[nl][kl]);
  }
}

// ---------------- f32 -> bf16 cast (vectorized) ----------------
__global__ __launch_bounds__(256) void cast_bf(const float* __restrict__ x,
                                               short* __restrict__ o, int n4) {
  const int i = blockIdx.x * 256 + threadIdx.x;
  if (i >= n4) return;
  float4v v = *(const float4v*)(x + (size_t)i * 4);
  ushort4v p;
  p[0] = (unsigned short)f2bf(v[0]);
  p[1] = (unsigned short)f2bf(v[1]);
  p[2] = (unsigned short)f2bf(v[2]);
  p[3] = (unsigned short)f2bf(v[3]);
  *(ushort4v*)(o + (size_t)i * 4) = p;
}

// ---------------- GEMM: C[M,N] = A[M,K](bf16) x Bt[N,K](bf16)^T, fused epilogues ----
enum { EPI_Q = 0, EPI_K = 1, EPI_V = 2, EPI_WO = 3, EPI_RELU = 4, EPI_FF = 5 };

template <int EPI>
__global__ __launch_bounds__(256) void gemm_bt(const short* __restrict__ A,
                                               const short* __restrict__ Bt,
                                               const float* __restrict__ bias,
                                               const float* __restrict__ extra,
                                               void* __restrict__ outp,
                                               int M, int N, int K) {
  __shared__ short As[128 * 64];
  __shared__ short Bs[128 * 64];
  const int tid = threadIdx.x;
  const int lane = tid & 63, wid = tid >> 6;
  const int wr = wid >> 1, wc = wid & 1;
  const int l16 = lane & 15, lg = lane >> 4;
  const int brow = blockIdx.y * 128, bcol = blockIdx.x * 128;

  f32x4 acc[4][4];
#pragma unroll
  for (int i = 0; i < 4; ++i)
#pragma unroll
    for (int j = 0; j < 4; ++j) acc[i][j] = (f32x4){0.f, 0.f, 0.f, 0.f};

  for (int kt = 0; kt < K; kt += 64) {
    __syncthreads();
#pragma unroll
    for (int i = 0; i < 4; ++i) {
      const int c = wid * 256 + i * 64 + lane;      // chunk id for this lane
      const int row = c >> 3;
      const int gc = (c & 7) ^ (row & 7);           // pre-swizzled global source
      gll16(A + (size_t)(brow + row) * K + kt + gc * 8,
            (char*)As + (wid * 256 + i * 64) * 16); // wave-uniform LDS base
      gll16(Bt + (size_t)(bcol + row) * K + kt + gc * 8,
            (char*)Bs + (wid * 256 + i * 64) * 16);
    }
    __syncthreads();
#pragma unroll
    for (int kc = 0; kc < 2; ++kc) {
      short8 af[4], bfr[4];
#pragma unroll
      for (int m = 0; m < 4; ++m) {
        const int row = wr * 64 + m * 16 + l16;
        const int ch = (kc * 4 + lg) ^ (row & 7);
        af[m] = *(const short8*)((const char*)As + row * 128 + ch * 16);
      }
#pragma unroll
      for (int n = 0; n < 4; ++n) {
        const int row = wc * 64 + n * 16 + l16;
        const int ch = (kc * 4 + lg) ^ (row & 7);
        bfr[n] = *(const short8*)((const char*)Bs + row * 128 + ch * 16);
      }
#pragma unroll
      for (int m = 0; m < 4; ++m)
#pragma unroll
        for (int n = 0; n < 4; ++n)
          acc[m][n] = __builtin_amdgcn_mfma_f32_16x16x32_bf16(af[m], bfr[n],
                                                              acc[m][n], 0, 0, 0);
    }
  }

  const int mbase = brow + wr * 64;
  const int nbase = bcol + wc * 64;

  if constexpr (EPI == EPI_Q || EPI == EPI_K) {
    short* o = (short*)outp;
#pragma unroll
    for (int ni = 0; ni < 4; ++ni) {
      const int n = nbase + ni * 16 + l16;
      const float bv = bias[n];
      const int h = n >> 6, dk = n & 63;
#pragma unroll
      for (int mi = 0; mi < 4; ++mi) {
#pragma unroll
        for (int r = 0; r < 4; ++r) {
          const int m = mbase + mi * 16 + lg * 4 + r;
          const int bidx = m >> 11, sidx = m & 2047;
          float v = acc[mi][ni][r] + bv;
          if constexpr (EPI == EPI_Q) v *= 0.125f;  // 1/sqrt(DK)
          o[(((size_t)bidx * NHEADS + h) * SEQ + sidx) * 64 + dk] = f2bf(v);
        }
      }
    }
  } else if constexpr (EPI == EPI_V) {
    // store transposed: Vt[b,h,dk,s], 4 consecutive s per lane -> 8B packed store
    short* o = (short*)outp;
#pragma unroll
    for (int ni = 0; ni < 4; ++ni) {
      const int n = nbase + ni * 16 + l16;
      const float bv = bias[n];
      const int h = n >> 6, dk = n & 63;
#pragma unroll
      for (int mi = 0; mi < 4; ++mi) {
        const int m0 = mbase + mi * 16 + lg * 4;
        const int bidx = m0 >> 11, s0 = m0 & 2047;
        ushort4v pk;
#pragma unroll
        for (int r = 0; r < 4; ++r) pk[r] = (unsigned short)f2bf(acc[mi][ni][r] + bv);
        *(ushort4v*)(o + (((size_t)bidx * NHEADS + h) * 64 + dk) * SEQ + s0) = pk;
      }
    }
  } else if constexpr (EPI == EPI_WO || EPI == EPI_FF) {
    // f32 out = acc + bias + residual(extra)
    float* o = (float*)outp;
#pragma unroll
    for (int ni = 0; ni < 4; ++ni) {
      const int n = nbase + ni * 16 + l16;
      const float bv = bias[n];
#pragma unroll
      for (int mi = 0; mi < 4; ++mi)
#pragma unroll
        for (int r = 0; r < 4; ++r) {
          const int m = mbase + mi * 16 + lg * 4 + r;
          const size_t idx = (size_t)m * N + n;
          o[idx] = acc[mi][ni][r] + bv + extra[idx];
        }
    }
  } else {  // EPI_RELU -> bf16
    short* o = (short*)outp;
#pragma unroll
    for (int ni = 0; ni < 4; ++ni) {
      const int n = nbase + ni * 16 + l16;
      const float bv = bias[n];
#pragma unroll
      for (int mi = 0; mi < 4; ++mi)
#pragma unroll
        for (int r = 0; r < 4; ++r) {
          const int m = mbase + mi * 16 + lg * 4 + r;
          o[(size_t)m * N + n] = f2bf(fmaxf(acc[mi][ni][r] + bv, 0.f));
        }
    }
  }
}

// ---------------- flash attention: QBLK=64 (4 waves x 16 rows), KVBLK=64 ----------
__global__ __launch_bounds__(256) void attn_fa(const short* __restrict__ Q,   // [BH,S,64] (pre-scaled 1/8)
                                               const short* __restrict__ Kb,  // [BH,S,64]
                                               const short* __restrict__ Vt,  // [BH,64,S]
                                               const int* __restrict__ mask,  // [B,S]
                                               short* __restrict__ ctx) {     // [B,S,768]
  __shared__ short Ks[64 * 64];
  __shared__ short Vs[64 * 64];
  __shared__ short Ps[4 * 16 * 64];  // per-wave P tile
  const int tid = threadIdx.x;
  const int lane = tid & 63, w = tid >> 6;
  const int l16 = lane & 15, lg = lane >> 4;
  const int bh = blockIdx.y;
  const int b = bh / NHEADS, h = bh % NHEADS;
  const int q0 = blockIdx.x * 64;

  // Q fragments in registers (A-frag: row=l16, k=lg*8+j)
  const short* qp = Q + ((size_t)bh * SEQ + q0 + w * 16 + l16) * 64;
  short8 qa[2];
  qa[0] = *(const short8*)(qp + lg * 8);
  qa[1] = *(const short8*)(qp + 32 + lg * 8);

  f32x4 o[4];
#pragma unroll
  for (int d = 0; d < 4; ++d) o[d] = (f32x4){0.f, 0.f, 0.f, 0.f};
  float mrow[4], lrow[4];
#pragma unroll
  for (int r = 0; r < 4; ++r) { mrow[r] = -1e30f; lrow[r] = 0.f; }

  for (int kv0 = 0; kv0 < SEQ; kv0 += 64) {
    __syncthreads();
#pragma unroll
    for (int i = 0; i < 2; ++i) {
      const int c = w * 128 + i * 64 + lane;
      const int row = c >> 3;
      const int gc = (c & 7) ^ (row & 7);
      gll16(Kb + ((size_t)bh * SEQ + kv0 + row) * 64 + gc * 8,
            (char*)Ks + (w * 128 + i * 64) * 16);
      gll16(Vt + ((size_t)bh * 64 + row) * SEQ + kv0 + gc * 8,
            (char*)Vs + (w * 128 + i * 64) * 16);
    }
    __syncthreads();

    // S = Q K^T  (rows=q: lg*4+r, cols=kv: l16 within nb block)
    f32x4 s[4];
#pragma unroll
    for (int nb = 0; nb < 4; ++nb) {
      s[nb] = (f32x4){0.f, 0.f, 0.f, 0.f};
#pragma unroll
      for (int kc = 0; kc < 2; ++kc) {
        const int row = nb * 16 + l16;
        const int ch = (kc * 4 + lg) ^ (row & 7);
        short8 kb = *(const short8*)((const char*)Ks + row * 128 + ch * 16);
        s[nb] = __builtin_amdgcn_mfma_f32_16x16x32_bf16(qa[kc], kb, s[nb], 0, 0, 0);
      }
    }
    // mask (all-ones in practice; keep for fidelity)
#pragma unroll
    for (int nb = 0; nb < 4; ++nb) {
      const int kv = kv0 + nb * 16 + l16;
      if (mask[(size_t)b * SEQ + kv] == 0) {
#pragma unroll
        for (int r = 0; r < 4; ++r) s[nb][r] = -1e9f;
      }
    }
    // online softmax
#pragma unroll
    for (int r = 0; r < 4; ++r) {
      float v = fmaxf(fmaxf(s[0][r], s[1][r]), fmaxf(s[2][r], s[3][r]));
      v = fmaxf(v, __shfl_xor(v, 1));
      v = fmaxf(v, __shfl_xor(v, 2));
      v = fmaxf(v, __shfl_xor(v, 4));
      v = fmaxf(v, __shfl_xor(v, 8));
      const float mn = fmaxf(mrow[r], v);
      const float corr = __expf(mrow[r] - mn);
      float rs = 0.f;
#pragma unroll
      for (int nb = 0; nb < 4; ++nb) {
        const float p = __expf(s[nb][r] - mn);
        s[nb][r] = p;
        rs += p;
      }
      rs += __shfl_xor(rs, 1);
      rs += __shfl_xor(rs, 2);
      rs += __shfl_xor(rs, 4);
      rs += __shfl_xor(rs, 8);
      lrow[r] = lrow[r] * corr + rs;
      mrow[r] = mn;
#pragma unroll
      for (int d = 0; d < 4; ++d) o[d][r] *= corr;
    }
    // P -> bf16 -> per-wave LDS (swizzled), then reload as A-fragments
#pragma unroll
    for (int nb = 0; nb < 4; ++nb) {
#pragma unroll
      for (int r = 0; r < 4; ++r) {
        const int prow = lg * 4 + r;
        const int col = nb * 16 + l16;
        const int ch = (col >> 3) ^ (prow & 7);
        Ps[w * 1024 + prow * 64 + ch * 8 + (col & 7)] = f2bf(s[nb][r]);
      }
    }
#pragma unroll
    for (int kc = 0; kc < 2; ++kc) {
      const int prow = l16;
      const int pch = (kc * 4 + lg) ^ (prow & 7);
      short8 pa = *(const short8*)((const char*)Ps + w * 2048 + prow * 128 + pch * 16);
#pragma unroll
      for (int d = 0; d < 4; ++d) {
        const int vrow = d * 16 + l16;
        const int vch = (kc * 4 + lg) ^ (vrow & 7);
        short8 vb = *(const short8*)((const char*)Vs + vrow * 128 + vch * 16);
        o[d] = __builtin_amdgcn_mfma_f32_16x16x32_bf16(pa, vb, o[d], 0, 0, 0);
      }
    }
  }

  // normalize + write ctx[b, s, h*64+dk] (bf16)
  short* cp = ctx + ((size_t)b * SEQ + q0 + w * 16) * D_MODEL + h * 64;
#pragma unroll
  for (int r = 0; r < 4; ++r) {
    const float inv = 1.f / lrow[r];
    const int qrow = lg * 4 + r;
#pragma unroll
    for (int d = 0; d < 4; ++d)
      cp[(size_t)qrow * D_MODEL + d * 16 + l16] = f2bf(o[d][r] * inv);
  }
}

// ---------------- LayerNorm over D=768, one block per row ----------------
template <int WRITE_BF>
__global__ __launch_bounds__(256) void ln_k(const float* __restrict__ y,
                                            const float* __restrict__ gw,
                                            const float* __restrict__ bw,
                                            float* __restrict__ of,
                                            short* __restrict__ ob) {
  const int row = blockIdx.x, t = threadIdx.x;
  const float* yr = y + (size_t)row * D_MODEL;
  const float v0 = yr[t], v1 = yr[t + 256], v2 = yr[t + 512];
  float s = v0 + v1 + v2;
  float q = v0 * v0 + v1 * v1 + v2 * v2;
#pragma unroll
  for (int m = 1; m < 64; m <<= 1) {
    s += __shfl_xor(s, m);
    q += __shfl_xor(q, m);
  }
  __shared__ float ss[4], qs[4];
  const int w = t >> 6;
  if ((t & 63) == 0) { ss[w] = s; qs[w] = q; }
  __syncthreads();
  s = ss[0] + ss[1] + ss[2] + ss[3];
  q = qs[0] + qs[1] + qs[2] + qs[3];
  const float mu = s * (1.f / D_MODEL);
  const float rs = rsqrtf(q * (1.f / D_MODEL) - mu * mu + 1e-5f);
  const float o0 = (v0 - mu) * rs * gw[t] + bw[t];
  const float o1 = (v1 - mu) * rs * gw[t + 256] + bw[t + 256];
  const float o2 = (v2 - mu) * rs * gw[t + 512] + bw[t + 512];
  float* orow = of + (size_t)row * D_MODEL;
  orow[t] = o0;
  orow[t + 256] = o1;
  orow[t + 512] = o2;
  if constexpr (WRITE_BF) {
    short* obr = ob + (size_t)row * D_MODEL;
    obr[t] = f2bf(o0);
    obr[t + 256] = f2bf(o1);
    obr[t + 512] = f2bf(o2);
  }
}

// ---------------- launch ----------------
extern "C" void kernel_launch(void* const* d_in, const int* in_sizes, int n_in,
                              void* d_out, int out_size, void* d_ws, size_t ws_size,
                              hipStream_t stream) {
  const float* emb = (const float*)d_in[0];
  const int* mask = (const int*)d_in[1];
  const float* Wq = (const float*)d_in[2];
  const float* bq = (const float*)d_in[3];
  const float* Wk = (const float*)d_in[4];
  const float* bk = (const float*)d_in[5];
  const float* Wv = (const float*)d_in[6];
  const float* bv = (const float*)d_in[7];
  const float* Wo = (const float*)d_in[8];
  const float* bo = (const float*)d_in[9];
  const float* W1 = (const float*)d_in[10];
  const float* b1 = (const float*)d_in[11];
  const float* W2 = (const float*)d_in[12];
  const float* b2 = (const float*)d_in[13];
  const float* lng = (const float*)d_in[14];
  const float* lnb = (const float*)d_in[15];

  char* ws = (char*)d_ws;
  size_t off = 0;
  auto alloc = [&](size_t bytes) -> char* {
    char* p = ws + off;
    off = (off + bytes + 255) & ~(size_t)255;
    return p;
  };
  const size_t DD = (size_t)D_MODEL * D_MODEL;          // 589824
  const size_t DF = (size_t)D_MODEL * FF_DIM;           // 2359296
  const size_t TD = (size_t)NTOK * D_MODEL;             // 6291456
  const size_t TF = (size_t)NTOK * FF_DIM;              // 25165824

  short* wqt = (short*)alloc(DD * 2);
  short* wkt = (short*)alloc(DD * 2);
  short* wvt = (short*)alloc(DD * 2);
  short* wot = (short*)alloc(DD * 2);
  short* w1t = (short*)alloc(DF * 2);
  short* w2t = (short*)alloc(DF * 2);
  short* x0  = (short*)alloc(TD * 2);   // embedding bf16; reused as ctx
  short* qb  = (short*)alloc(TD * 2);
  short* kb  = (short*)alloc(TD * 2);
  short* vtb = (short*)alloc(TD * 2);
  float* ares = (float*)alloc(TD * 4);  // attn_out + emb; reused as ffres
  float* xf  = (float*)alloc(TD * 4);
  short* xbf = (short*)alloc(TD * 2);
  short* hbf = (short*)alloc(TF * 2);
  short* ctx = x0;
  float* ffres = ares;

  // 1. weight cast+transpose
  wt_cast<<<dim3(12, 12), 256, 0, stream>>>(Wq, wqt, D_MODEL, D_MODEL);
  wt_cast<<<dim3(12, 12), 256, 0, stream>>>(Wk, wkt, D_MODEL, D_MODEL);
  wt_cast<<<dim3(12, 12), 256, 0, stream>>>(Wv, wvt, D_MODEL, D_MODEL);
  wt_cast<<<dim3(12, 12), 256, 0, stream>>>(Wo, wot, D_MODEL, D_MODEL);
  wt_cast<<<dim3(48, 12), 256, 0, stream>>>(W1, w1t, D_MODEL, FF_DIM);
  wt_cast<<<dim3(12, 48), 256, 0, stream>>>(W2, w2t, FF_DIM, D_MODEL);
  // 2. embedding -> bf16
  cast_bf<<<dim3((int)(TD / 4 / 256)), 256, 0, stream>>>(emb, x0, (int)(TD / 4));
  // 3. QKV projections
  gemm_bt<EPI_Q><<<dim3(6, 64), 256, 0, stream>>>(x0, wqt, bq, nullptr, qb, NTOK, D_MODEL, D_MODEL);
  gemm_bt<EPI_K><<<dim3(6, 64), 256, 0, stream>>>(x0, wkt, bk, nullptr, kb, NTOK, D_MODEL, D_MODEL);
  gemm_bt<EPI_V><<<dim3(6, 64), 256, 0, stream>>>(x0, wvt, bv, nullptr, vtb, NTOK, D_MODEL, D_MODEL);
  // 4. attention
  attn_fa<<<dim3(32, BATCH * NHEADS), 256, 0, stream>>>(qb, kb, vtb, mask, ctx);
  // 5. output proj + residual
  gemm_bt<EPI_WO><<<dim3(6, 64), 256, 0, stream>>>(ctx, wot, bo, emb, ares, NTOK, D_MODEL, D_MODEL);
  // 6. LN1 -> x (f32 + bf16)
  ln_k<1><<<dim3(NTOK), 256, 0, stream>>>(ares, lng, lnb, xf, xbf);
  // 7. FF up + relu
  gemm_bt<EPI_RELU><<<dim3(24, 64), 256, 0, stream>>>(xbf, w1t, b1, nullptr, hbf, NTOK, FF_DIM, D_MODEL);
  // 8. FF down + residual
  gemm_bt<EPI_FF><<<dim3(6, 64), 256, 0, stream>>>(hbf, w2t, b2, xf, ffres, NTOK, D_MODEL, FF_DIM);
  // 9. LN2 -> out
  ln_k<0><<<dim3(NTOK), 256, 0, stream>>>(ffres, lng, lnb, (float*)d_out, nullptr);
}

// Round 2
// 356.699 us; speedup vs baseline: 1.1919x; 1.1919x over previous
//
#include <hip/hip_runtime.h>

#define D_MODEL 768
#define NHEADS  12
#define SEQ     2048
#define BATCH   4
#define FF_DIM  3072
#define NTOK    (BATCH * SEQ)

typedef short short8 __attribute__((ext_vector_type(8)));
typedef float f32x4 __attribute__((ext_vector_type(4)));
typedef float f32x16 __attribute__((ext_vector_type(16)));
typedef int int4v __attribute__((ext_vector_type(4)));
typedef unsigned short ushort4v __attribute__((ext_vector_type(4)));
typedef float float4v __attribute__((ext_vector_type(4)));

__device__ __forceinline__ short f2bf(float x) {
  unsigned u = __builtin_bit_cast(unsigned, x);
  u += 0x7fffu + ((u >> 16) & 1u);   // RNE
  return (short)(u >> 16);
}

__device__ __forceinline__ int cvtpk(float a, float b) {
  int r;
  asm("v_cvt_pk_bf16_f32 %0, %1, %2" : "=v"(r) : "v"(a), "v"(b));
  return r;  // lo16 = bf16(a), hi16 = bf16(b)
}

__device__ __forceinline__ void gll16(const void* g, void* l) {
  __builtin_amdgcn_global_load_lds(
      (const __attribute__((address_space(1))) void*)g,
      (__attribute__((address_space(3))) void*)l, 16, 0, 0);
}

// ---------------- weight cast+transpose: W[K][N] f32 -> Wt[N][K] bf16 ----------------
__global__ __launch_bounds__(256) void wt_cast(const float* __restrict__ W,
                                               short* __restrict__ Wt, int K, int N) {
  __shared__ float T[64][65];
  const int t = threadIdx.x;
  const int c = t & 63, rb = t >> 6;
  const int k0 = blockIdx.y * 64, n0 = blockIdx.x * 64;
#pragma unroll
  for (int i = 0; i < 16; ++i) {
    const int r = rb * 16 + i;
    T[c][r] = W[(size_t)(k0 + r) * N + n0 + c];
  }
  __syncthreads();
#pragma unroll
  for (int j = 0; j < 16; ++j) {
    const int idx = t + j * 256;
    const int nl = idx >> 6, kl = idx & 63;
    Wt[(size_t)(n0 + nl) * K + k0 + kl] = f2bf(T[nl][kl]);
  }
}

// ---------------- f32 -> bf16 cast (vectorized) ----------------
__global__ __launch_bounds__(256) void cast_bf(const float* __restrict__ x,
                                               short* __restrict__ o, int n4) {
  const int i = blockIdx.x * 256 + threadIdx.x;
  if (i >= n4) return;
  float4v v = *(const float4v*)(x + (size_t)i * 4);
  ushort4v p;
  p[0] = (unsigned short)f2bf(v[0]);
  p[1] = (unsigned short)f2bf(v[1]);
  p[2] = (unsigned short)f2bf(v[2]);
  p[3] = (unsigned short)f2bf(v[3]);
  *(ushort4v*)(o + (size_t)i * 4) = p;
}

// ---------------- GEMM: C[M,N] = A[M,K](bf16) x Bt[N,K](bf16)^T, fused epilogues ----
enum { EPI_Q = 0, EPI_K = 1, EPI_V = 2, EPI_WO = 3, EPI_RELU = 4, EPI_FF = 5 };

template <int EPI>
__global__ __launch_bounds__(256) void gemm_bt(const short* __restrict__ A,
                                               const short* __restrict__ Bt,
                                               const float* __restrict__ bias,
                                               const float* __restrict__ extra,
                                               void* __restrict__ outp,
                                               int M, int N, int K) {
  __shared__ short As[128 * 64];
  __shared__ short Bs[128 * 64];
  const int tid = threadIdx.x;
  const int lane = tid & 63, wid = tid >> 6;
  const int wr = wid >> 1, wc = wid & 1;
  const int l16 = lane & 15, lg = lane >> 4;
  const int brow = blockIdx.y * 128, bcol = blockIdx.x * 128;

  f32x4 acc[4][4];
#pragma unroll
  for (int i = 0; i < 4; ++i)
#pragma unroll
    for (int j = 0; j < 4; ++j) acc[i][j] = (f32x4){0.f, 0.f, 0.f, 0.f};

  for (int kt = 0; kt < K; kt += 64) {
    __syncthreads();
#pragma unroll
    for (int i = 0; i < 4; ++i) {
      const int c = wid * 256 + i * 64 + lane;      // chunk id for this lane
      const int row = c >> 3;
      const int gc = (c & 7) ^ (row & 7);           // pre-swizzled global source
      gll16(A + (size_t)(brow + row) * K + kt + gc * 8,
            (char*)As + (wid * 256 + i * 64) * 16); // wave-uniform LDS base
      gll16(Bt + (size_t)(bcol + row) * K + kt + gc * 8,
            (char*)Bs + (wid * 256 + i * 64) * 16);
    }
    __syncthreads();
#pragma unroll
    for (int kc = 0; kc < 2; ++kc) {
      short8 af[4], bfr[4];
#pragma unroll
      for (int m = 0; m < 4; ++m) {
        const int row = wr * 64 + m * 16 + l16;
        const int ch = (kc * 4 + lg) ^ (row & 7);
        af[m] = *(const short8*)((const char*)As + row * 128 + ch * 16);
      }
#pragma unroll
      for (int n = 0; n < 4; ++n) {
        const int row = wc * 64 + n * 16 + l16;
        const int ch = (kc * 4 + lg) ^ (row & 7);
        bfr[n] = *(const short8*)((const char*)Bs + row * 128 + ch * 16);
      }
#pragma unroll
      for (int m = 0; m < 4; ++m)
#pragma unroll
        for (int n = 0; n < 4; ++n)
          acc[m][n] = __builtin_amdgcn_mfma_f32_16x16x32_bf16(af[m], bfr[n],
                                                              acc[m][n], 0, 0, 0);
    }
  }

  const int mbase = brow + wr * 64;
  const int nbase = bcol + wc * 64;

  if constexpr (EPI == EPI_Q || EPI == EPI_K) {
    short* o = (short*)outp;
#pragma unroll
    for (int ni = 0; ni < 4; ++ni) {
      const int n = nbase + ni * 16 + l16;
      const float bv = bias[n];
      const int h = n >> 6, dk = n & 63;
#pragma unroll
      for (int mi = 0; mi < 4; ++mi) {
#pragma unroll
        for (int r = 0; r < 4; ++r) {
          const int m = mbase + mi * 16 + lg * 4 + r;
          const int bidx = m >> 11, sidx = m & 2047;
          float v = acc[mi][ni][r] + bv;
          // 1/sqrt(DK) * log2(e): attn uses exp2-based softmax
          if constexpr (EPI == EPI_Q) v *= 0.125f * 1.44269504f;
          o[(((size_t)bidx * NHEADS + h) * SEQ + sidx) * 64 + dk] = f2bf(v);
        }
      }
    }
  } else if constexpr (EPI == EPI_V) {
    // store transposed: Vt[b,h,dk,s], 4 consecutive s per lane -> 8B packed store
    short* o = (short*)outp;
#pragma unroll
    for (int ni = 0; ni < 4; ++ni) {
      const int n = nbase + ni * 16 + l16;
      const float bv = bias[n];
      const int h = n >> 6, dk = n & 63;
#pragma unroll
      for (int mi = 0; mi < 4; ++mi) {
        const int m0 = mbase + mi * 16 + lg * 4;
        const int bidx = m0 >> 11, s0 = m0 & 2047;
        ushort4v pk;
#pragma unroll
        for (int r = 0; r < 4; ++r) pk[r] = (unsigned short)f2bf(acc[mi][ni][r] + bv);
        *(ushort4v*)(o + (((size_t)bidx * NHEADS + h) * 64 + dk) * SEQ + s0) = pk;
      }
    }
  } else if constexpr (EPI == EPI_WO || EPI == EPI_FF) {
    // f32 out = acc + bias + residual(extra)
    float* o = (float*)outp;
#pragma unroll
    for (int ni = 0; ni < 4; ++ni) {
      const int n = nbase + ni * 16 + l16;
      const float bv = bias[n];
#pragma unroll
      for (int mi = 0; mi < 4; ++mi)
#pragma unroll
        for (int r = 0; r < 4; ++r) {
          const int m = mbase + mi * 16 + lg * 4 + r;
          const size_t idx = (size_t)m * N + n;
          o[idx] = acc[mi][ni][r] + bv + extra[idx];
        }
    }
  } else {  // EPI_RELU -> bf16
    short* o = (short*)outp;
#pragma unroll
    for (int ni = 0; ni < 4; ++ni) {
      const int n = nbase + ni * 16 + l16;
      const float bv = bias[n];
#pragma unroll
      for (int mi = 0; mi < 4; ++mi)
#pragma unroll
        for (int r = 0; r < 4; ++r) {
          const int m = mbase + mi * 16 + lg * 4 + r;
          o[(size_t)m * N + n] = f2bf(fmaxf(acc[mi][ni][r] + bv, 0.f));
        }
    }
  }
}

// ---------------- flash attention v2: swapped QK^T, 32x32x16 MFMA ----------------
// 4 waves x 32 q-rows, KVBLK=64, double-buffered XOR-swizzled K/V LDS,
// in-register softmax (T12 cvt_pk + lane-swap), defer-max (T13, log2-domain).
__global__ __launch_bounds__(256, 3) void attn_fa2(
    const short* __restrict__ Q,   // [BH,S,64] pre-scaled by 0.125*log2e
    const short* __restrict__ Kb,  // [BH,S,64]
    const short* __restrict__ Vt,  // [BH,64,S]
    const int* __restrict__ mask,  // [B,S]
    short* __restrict__ ctx) {     // [B,S,768]
  __shared__ short KsA[64 * 64], KsB[64 * 64];
  __shared__ short VsA[64 * 64], VsB[64 * 64];
  __shared__ float bc[4][32];
  const int tid = threadIdx.x;
  const int lane = tid & 63, w = tid >> 6;
  const int l31 = lane & 31, hi = lane >> 5;
  const int bh = blockIdx.y, b = bh / NHEADS, h = bh % NHEADS;
  const int q0 = blockIdx.x * 128 + w * 32;

  // Q B-fragments: col=q=lane&31, k=dk=slot*16+hi*8+j
  const short* qp = Q + ((size_t)bh * SEQ + q0 + l31) * 64;
  short8 qf[4];
#pragma unroll
  for (int s = 0; s < 4; ++s) qf[s] = *(const short8*)(qp + s * 16 + hi * 8);

  f32x16 o0, o1;
#pragma unroll
  for (int i = 0; i < 16; ++i) { o0[i] = 0.f; o1[i] = 0.f; }
  float m = -1e30f, l = 0.f;

  auto stage = [&](short* Ksd, short* Vsd, int kv0) {
#pragma unroll
    for (int i = 0; i < 2; ++i) {
      const int c = i * 256 + tid;
      const int row = c >> 3, ch = c & 7;
      const int gc = ch ^ (row & 7);  // pre-swizzled source, linear LDS dest
      gll16(Kb + ((size_t)bh * SEQ + kv0 + row) * 64 + gc * 8,
            (char*)Ksd + (i * 256 + w * 64) * 16);
      gll16(Vt + ((size_t)bh * 64 + row) * SEQ + kv0 + gc * 8,
            (char*)Vsd + (i * 256 + w * 64) * 16);
    }
  };

  stage(KsA, VsA, 0);
  __syncthreads();

  for (int t = 0; t < SEQ / 64; ++t) {
    const short* Ksc = (t & 1) ? KsB : KsA;
    const short* Vsc = (t & 1) ? VsB : VsA;
    if (t + 1 < SEQ / 64)
      stage((t & 1) ? KsA : KsB, (t & 1) ? VsA : VsB, (t + 1) * 64);

    // ---- S^T = K Q : D[kv][q], q = lane&31, kv = c*32 + crow(r,hi) ----
    f32x16 s0, s1;
#pragma unroll
    for (int i = 0; i < 16; ++i) { s0[i] = 0.f; s1[i] = 0.f; }
#pragma unroll
    for (int slot = 0; slot < 4; ++slot) {
      const int ch0 = (slot * 2 + hi) ^ (l31 & 7);
      short8 a0 = *(const short8*)((const char*)Ksc + l31 * 128 + ch0 * 16);
      s0 = __builtin_amdgcn_mfma_f32_32x32x16_bf16(a0, qf[slot], s0, 0, 0, 0);
      short8 a1 = *(const short8*)((const char*)Ksc + (32 + l31) * 128 + ch0 * 16);
      s1 = __builtin_amdgcn_mfma_f32_32x32x16_bf16(a1, qf[slot], s1, 0, 0, 0);
    }

    // ---- mask (rare path; all-ones in this benchmark) ----
    const int mv = mask[(size_t)b * SEQ + t * 64 + lane];
    if (__any(mv == 0)) {
#pragma unroll
      for (int r = 0; r < 16; ++r) {
        const int cr = (r & 3) + 8 * (r >> 2) + 4 * hi;
        if (__shfl(mv, cr) == 0) s0[r] = -1e9f;
        if (__shfl(mv, 32 + cr) == 0) s1[r] = -1e9f;
      }
    }

    // ---- online softmax (log2 domain: scores already scaled by log2e) ----
    float pmax = s0[0];
#pragma unroll
    for (int r = 1; r < 16; ++r) pmax = fmaxf(pmax, s0[r]);
#pragma unroll
    for (int r = 0; r < 16; ++r) pmax = fmaxf(pmax, s1[r]);
    pmax = fmaxf(pmax, __shfl_xor(pmax, 32));
    if (!__all(pmax - m <= 11.0f)) {  // defer-max: rescale only on real growth
      const float mn = fmaxf(m, pmax);
      const float corr = exp2f(m - mn);
      if (lane < 32) bc[w][l31] = corr;
#pragma unroll
      for (int r = 0; r < 16; ++r) {
        const float cf = bc[w][(r & 3) + 8 * (r >> 2) + 4 * hi];
        o0[r] *= cf;
        o1[r] *= cf;
      }
      l *= corr;
      m = mn;
    }
    float rs = 0.f;
#pragma unroll
    for (int r = 0; r < 16; ++r) {
      s0[r] = exp2f(s0[r] - m);
      rs += s0[r];
      s1[r] = exp2f(s1[r] - m);
      rs += s1[r];
    }
    rs += __shfl_xor(rs, 32);
    l += rs;

    // ---- P -> bf16 A-frags (cvt_pk + lane^32 swap) + PV ----
#pragma unroll
    for (int c = 0; c < 2; ++c) {
      const f32x16 sc = c ? s1 : s0;
#pragma unroll
      for (int ks = 0; ks < 2; ++ks) {
        const int rb = ks * 8;
        const int x0 = cvtpk(sc[rb + 0], sc[rb + 1]);
        const int y0 = cvtpk(sc[rb + 4], sc[rb + 5]);
        const int x1 = cvtpk(sc[rb + 2], sc[rb + 3]);
        const int y1 = cvtpk(sc[rb + 6], sc[rb + 7]);
        const int ys0 = __shfl_xor(y0, 32);
        const int xs0 = __shfl_xor(x0, 32);
        const int ys1 = __shfl_xor(y1, 32);
        const int xs1 = __shfl_xor(x1, 32);
        int4v pw;
        pw[0] = hi ? ys0 : x0;   // k elems +0,+1
        pw[1] = hi ? ys1 : x1;   // +2,+3
        pw[2] = hi ? y0 : xs0;   // +4,+5
        pw[3] = hi ? y1 : xs1;   // +6,+7
        const short8 pa = __builtin_bit_cast(short8, pw);
        const int vslot = c * 2 + ks;
#pragma unroll
        for (int dblk = 0; dblk < 2; ++dblk) {
          const int vr = dblk * 32 + l31;
          const int vch = (vslot * 2 + hi) ^ (l31 & 7);
          short8 vb = *(const short8*)((const char*)Vsc + vr * 128 + vch * 16);
          if (dblk == 0)
            o0 = __builtin_amdgcn_mfma_f32_32x32x16_bf16(pa, vb, o0, 0, 0, 0);
          else
            o1 = __builtin_amdgcn_mfma_f32_32x32x16_bf16(pa, vb, o1, 0, 0, 0);
        }
      }
    }
    __syncthreads();
  }

  // ---- epilogue: broadcast 1/l to O layout, write ctx ----
  if (lane < 32) bc[w][l31] = 1.f / l;
#pragma unroll
  for (int r = 0; r < 16; ++r) {
    const int q = (r & 3) + 8 * (r >> 2) + 4 * hi;
    const float inv = bc[w][q];
    short* cp = ctx + ((size_t)b * SEQ + q0 + q) * D_MODEL + h * 64;
    cp[l31] = f2bf(o0[r] * inv);
    cp[32 + l31] = f2bf(o1[r] * inv);
  }
}

// ---------------- LayerNorm over D=768, one block per row ----------------
template <int WRITE_BF>
__global__ __launch_bounds__(256) void ln_k(const float* __restrict__ y,
                                            const float* __restrict__ gw,
                                            const float* __restrict__ bw,
                                            float* __restrict__ of,
                                            short* __restrict__ ob) {
  const int row = blockIdx.x, t = threadIdx.x;
  const float* yr = y + (size_t)row * D_MODEL;
  const float v0 = yr[t], v1 = yr[t + 256], v2 = yr[t + 512];
  float s = v0 + v1 + v2;
  float q = v0 * v0 + v1 * v1 + v2 * v2;
#pragma unroll
  for (int m = 1; m < 64; m <<= 1) {
    s += __shfl_xor(s, m);
    q += __shfl_xor(q, m);
  }
  __shared__ float ss[4], qs[4];
  const int w = t >> 6;
  if ((t & 63) == 0) { ss[w] = s; qs[w] = q; }
  __syncthreads();
  s = ss[0] + ss[1] + ss[2] + ss[3];
  q = qs[0] + qs[1] + qs[2] + qs[3];
  const float mu = s * (1.f / D_MODEL);
  const float rs = rsqrtf(q * (1.f / D_MODEL) - mu * mu + 1e-5f);
  const float o0 = (v0 - mu) * rs * gw[t] + bw[t];
  const float o1 = (v1 - mu) * rs * gw[t + 256] + bw[t + 256];
  const float o2 = (v2 - mu) * rs * gw[t + 512] + bw[t + 512];
  float* orow = of + (size_t)row * D_MODEL;
  orow[t] = o0;
  orow[t + 256] = o1;
  orow[t + 512] = o2;
  if constexpr (WRITE_BF) {
    short* obr = ob + (size_t)row * D_MODEL;
    obr[t] = f2bf(o0);
    obr[t + 256] = f2bf(o1);
    obr[t + 512] = f2bf(o2);
  }
}

// ---------------- launch ----------------
extern "C" void kernel_launch(void* const* d_in, const int* in_sizes, int n_in,
                              void* d_out, int out_size, void* d_ws, size_t ws_size,
                              hipStream_t stream) {
  const float* emb = (const float*)d_in[0];
  const int* mask = (const int*)d_in[1];
  const float* Wq = (const float*)d_in[2];
  const float* bq = (const float*)d_in[3];
  const float* Wk = (const float*)d_in[4];
  const float* bk = (const float*)d_in[5];
  const float* Wv = (const float*)d_in[6];
  const float* bv = (const float*)d_in[7];
  const float* Wo = (const float*)d_in[8];
  const float* bo = (const float*)d_in[9];
  const float* W1 = (const float*)d_in[10];
  const float* b1 = (const float*)d_in[11];
  const float* W2 = (const float*)d_in[12];
  const float* b2 = (const float*)d_in[13];
  const float* lng = (const float*)d_in[14];
  const float* lnb = (const float*)d_in[15];

  char* ws = (char*)d_ws;
  size_t off = 0;
  auto alloc = [&](size_t bytes) -> char* {
    char* p = ws + off;
    off = (off + bytes + 255) & ~(size_t)255;
    return p;
  };
  const size_t DD = (size_t)D_MODEL * D_MODEL;
  const size_t DF = (size_t)D_MODEL * FF_DIM;
  const size_t TD = (size_t)NTOK * D_MODEL;
  const size_t TF = (size_t)NTOK * FF_DIM;

  short* wqt = (short*)alloc(DD * 2);
  short* wkt = (short*)alloc(DD * 2);
  short* wvt = (short*)alloc(DD * 2);
  short* wot = (short*)alloc(DD * 2);
  short* w1t = (short*)alloc(DF * 2);
  short* w2t = (short*)alloc(DF * 2);
  short* x0  = (short*)alloc(TD * 2);   // embedding bf16; reused as ctx
  short* qb  = (short*)alloc(TD * 2);
  short* kb  = (short*)alloc(TD * 2);
  short* vtb = (short*)alloc(TD * 2);
  float* ares = (float*)alloc(TD * 4);  // attn_out + emb; reused as ffres
  float* xf  = (float*)alloc(TD * 4);
  short* xbf = (short*)alloc(TD * 2);
  short* hbf = (short*)alloc(TF * 2);
  short* ctx = x0;
  float* ffres = ares;

  wt_cast<<<dim3(12, 12), 256, 0, stream>>>(Wq, wqt, D_MODEL, D_MODEL);
  wt_cast<<<dim3(12, 12), 256, 0, stream>>>(Wk, wkt, D_MODEL, D_MODEL);
  wt_cast<<<dim3(12, 12), 256, 0, stream>>>(Wv, wvt, D_MODEL, D_MODEL);
  wt_cast<<<dim3(12, 12), 256, 0, stream>>>(Wo, wot, D_MODEL, D_MODEL);
  wt_cast<<<dim3(48, 12), 256, 0, stream>>>(W1, w1t, D_MODEL, FF_DIM);
  wt_cast<<<dim3(12, 48), 256, 0, stream>>>(W2, w2t, FF_DIM, D_MODEL);
  cast_bf<<<dim3((int)(TD / 4 / 256)), 256, 0, stream>>>(emb, x0, (int)(TD / 4));
  gemm_bt<EPI_Q><<<dim3(6, 64), 256, 0, stream>>>(x0, wqt, bq, nullptr, qb, NTOK, D_MODEL, D_MODEL);
  gemm_bt<EPI_K><<<dim3(6, 64), 256, 0, stream>>>(x0, wkt, bk, nullptr, kb, NTOK, D_MODEL, D_MODEL);
  gemm_bt<EPI_V><<<dim3(6, 64), 256, 0, stream>>>(x0, wvt, bv, nullptr, vtb, NTOK, D_MODEL, D_MODEL);
  attn_fa2<<<dim3(16, BATCH * NHEADS), 256, 0, stream>>>(qb, kb, vtb, mask, ctx);
  gemm_bt<EPI_WO><<<dim3(6, 64), 256, 0, stream>>>(ctx, wot, bo, emb, ares, NTOK, D_MODEL, D_MODEL);
  ln_k<1><<<dim3(NTOK), 256, 0, stream>>>(ares, lng, lnb, xf, xbf);
  gemm_bt<EPI_RELU><<<dim3(24, 64), 256, 0, stream>>>(xbf, w1t, b1, nullptr, hbf, NTOK, FF_DIM, D_MODEL);
  gemm_bt<EPI_FF><<<dim3(6, 64), 256, 0, stream>>>(hbf, w2t, b2, xf, ffres, NTOK, D_MODEL, FF_DIM);
  ln_k<0><<<dim3(NTOK), 256, 0, stream>>>(ffres, lng, lnb, (float*)d_out, nullptr);
}

// Round 3
// 306.547 us; speedup vs baseline: 1.3869x; 1.1636x over previous
//
#include <hip/hip_runtime.h>

#define D_MODEL 768
#define NHEADS  12
#define SEQ     2048
#define BATCH   4
#define FF_DIM  3072
#define NTOK    (BATCH * SEQ)

typedef short short8 __attribute__((ext_vector_type(8)));
typedef float f32x4 __attribute__((ext_vector_type(4)));
typedef float f32x16 __attribute__((ext_vector_type(16)));
typedef int int4v __attribute__((ext_vector_type(4)));
typedef int int2v __attribute__((ext_vector_type(2)));
typedef unsigned short ushort4v __attribute__((ext_vector_type(4)));
typedef float float4v __attribute__((ext_vector_type(4)));

__device__ __forceinline__ short f2bf(float x) {
  unsigned u = __builtin_bit_cast(unsigned, x);
  u += 0x7fffu + ((u >> 16) & 1u);   // RNE
  return (short)(u >> 16);
}
__device__ __forceinline__ float bf2f(short x) {
  return __builtin_bit_cast(float, ((unsigned)(unsigned short)x) << 16);
}
__device__ __forceinline__ int cvtpk(float a, float b) {
  int r;
  asm("v_cvt_pk_bf16_f32 %0, %1, %2" : "=v"(r) : "v"(a), "v"(b));
  return r;  // lo16 = bf16(a), hi16 = bf16(b)
}
__device__ __forceinline__ void gll16(const void* g, void* l) {
  __builtin_amdgcn_global_load_lds(
      (const __attribute__((address_space(1))) void*)g,
      (__attribute__((address_space(3))) void*)l, 16, 0, 0);
}

// ---------------- prep: all weight transposes + bias concat + emb cast ----------------
__device__ __forceinline__ void wt_tile(float (*T)[65], const float* __restrict__ W,
                                        short* __restrict__ Wt, int K, int N,
                                        int bx, int by, int t) {
  const int c = t & 63, rb = t >> 6;
  const int k0 = by * 64, n0 = bx * 64;
#pragma unroll
  for (int i = 0; i < 16; ++i) {
    const int r = rb * 16 + i;
    T[c][r] = W[(size_t)(k0 + r) * N + n0 + c];
  }
  __syncthreads();
#pragma unroll
  for (int j = 0; j < 16; ++j) {
    const int idx = t + j * 256;
    const int nl = idx >> 6, kl = idx & 63;
    Wt[(size_t)(n0 + nl) * K + k0 + kl] = f2bf(T[nl][kl]);
  }
}

__global__ __launch_bounds__(256) void prep(
    const float* __restrict__ Wq, const float* __restrict__ Wk, const float* __restrict__ Wv,
    const float* __restrict__ Wo, const float* __restrict__ W1, const float* __restrict__ W2,
    const float* __restrict__ bq, const float* __restrict__ bk, const float* __restrict__ bv,
    const float* __restrict__ emb,
    short* __restrict__ wqkvt, short* __restrict__ wot, short* __restrict__ w1t,
    short* __restrict__ w2t, float* __restrict__ bqkv, short* __restrict__ x0) {
  __shared__ float T[64][65];
  const int bi = blockIdx.x;
  const int t = threadIdx.x;
  if (bi < 432) {
    const int s = bi / 144, l = bi % 144;
    const float* W = (s == 0) ? Wq : (s == 1) ? Wk : Wv;
    wt_tile(T, W, wqkvt + (size_t)s * 768 * 768, 768, 768, l % 12, l / 12, t);
  } else if (bi < 576) {
    const int l = bi - 432;
    wt_tile(T, Wo, wot, 768, 768, l % 12, l / 12, t);
  } else if (bi < 1152) {
    const int l = bi - 576;
    wt_tile(T, W1, w1t, 768, 3072, l % 48, l / 48, t);
  } else if (bi < 1728) {
    const int l = bi - 1152;
    wt_tile(T, W2, w2t, 3072, 768, l % 12, l / 12, t);
  } else if (bi == 1728) {
#pragma unroll
    for (int j = 0; j < 9; ++j) {
      const int i = t + j * 256;
      bqkv[i] = (i < 768) ? bq[i] : (i < 1536) ? bk[i - 768] : bv[i - 1536];
    }
  } else {
    const int i = (bi - 1729) * 256 + t;
    float4v v = *(const float4v*)(emb + (size_t)i * 4);
    ushort4v p;
    p[0] = (unsigned short)f2bf(v[0]);
    p[1] = (unsigned short)f2bf(v[1]);
    p[2] = (unsigned short)f2bf(v[2]);
    p[3] = (unsigned short)f2bf(v[3]);
    *(ushort4v*)(x0 + (size_t)i * 4) = p;
  }
}

// ---------------- GEMM: C[M,N] = A[M,K](bf16) x Bt[N,K](bf16)^T, fused epilogues ----
enum { EPI_QKV = 0, EPI_WO = 1, EPI_RELU = 2, EPI_FF = 3 };

template <int EPI>
__global__ __launch_bounds__(256) void gemm_bt(const short* __restrict__ A,
                                               const short* __restrict__ Bt,
                                               const float* __restrict__ bias,
                                               const float* __restrict__ extraF,
                                               const short* __restrict__ extraB,
                                               void* __restrict__ outp,
                                               int M, int N, int K) {
  __shared__ short As[128 * 64];
  __shared__ short Bs[128 * 64];
  const int tid = threadIdx.x;
  const int lane = tid & 63, wid = tid >> 6;
  const int wr = wid >> 1, wc = wid & 1;
  const int l16 = lane & 15, lg = lane >> 4;
  const int brow = blockIdx.y * 128, bcol = blockIdx.x * 128;

  f32x4 acc[4][4];
#pragma unroll
  for (int i = 0; i < 4; ++i)
#pragma unroll
    for (int j = 0; j < 4; ++j) acc[i][j] = (f32x4){0.f, 0.f, 0.f, 0.f};

  for (int kt = 0; kt < K; kt += 64) {
    __syncthreads();
#pragma unroll
    for (int i = 0; i < 4; ++i) {
      const int c = wid * 256 + i * 64 + lane;
      const int row = c >> 3;
      const int gc = (c & 7) ^ (row & 7);           // pre-swizzled global source
      gll16(A + (size_t)(brow + row) * K + kt + gc * 8,
            (char*)As + (wid * 256 + i * 64) * 16);
      gll16(Bt + (size_t)(bcol + row) * K + kt + gc * 8,
            (char*)Bs + (wid * 256 + i * 64) * 16);
    }
    __syncthreads();
#pragma unroll
    for (int kc = 0; kc < 2; ++kc) {
      short8 af[4], bfr[4];
#pragma unroll
      for (int m = 0; m < 4; ++m) {
        const int row = wr * 64 + m * 16 + l16;
        const int ch = (kc * 4 + lg) ^ (row & 7);
        af[m] = *(const short8*)((const char*)As + row * 128 + ch * 16);
      }
#pragma unroll
      for (int n = 0; n < 4; ++n) {
        const int row = wc * 64 + n * 16 + l16;
        const int ch = (kc * 4 + lg) ^ (row & 7);
        bfr[n] = *(const short8*)((const char*)Bs + row * 128 + ch * 16);
      }
#pragma unroll
      for (int m = 0; m < 4; ++m)
#pragma unroll
        for (int n = 0; n < 4; ++n)
          acc[m][n] = __builtin_amdgcn_mfma_f32_16x16x32_bf16(af[m], bfr[n],
                                                              acc[m][n], 0, 0, 0);
    }
  }

  const int mbase = brow + wr * 64;
  const int nbase = bcol + wc * 64;

  if constexpr (EPI == EPI_QKV) {
    // outp = contiguous qkv base: qb | kb | vtb, each [BH,S,64] (vtb = [BH,64,S])
    short* qb_ = (short*)outp;
    short* kb_ = qb_ + (size_t)NTOK * D_MODEL;
    short* vt_ = kb_ + (size_t)NTOK * D_MODEL;
    const int type = nbase / 768;  // block-uniform
#pragma unroll
    for (int ni = 0; ni < 4; ++ni) {
      const int n = nbase + ni * 16 + l16;
      const float bv = bias[n];
      const int ncol = n - type * 768;
      const int h = ncol >> 6, dk = ncol & 63;
      if (type == 2) {  // V: transposed store [bh][dk][s]
#pragma unroll
        for (int mi = 0; mi < 4; ++mi) {
          const int m0 = mbase + mi * 16 + lg * 4;
          const int bidx = m0 >> 11, s0 = m0 & 2047;
          ushort4v pk;
#pragma unroll
          for (int r = 0; r < 4; ++r) pk[r] = (unsigned short)f2bf(acc[mi][ni][r] + bv);
          *(ushort4v*)(vt_ + (((size_t)bidx * NHEADS + h) * 64 + dk) * SEQ + s0) = pk;
        }
      } else {
        short* o = (type == 0) ? qb_ : kb_;
        const float sc = (type == 0) ? 0.125f * 1.44269504f : 1.f;  // Q: 1/sqrt(DK)*log2e
#pragma unroll
        for (int mi = 0; mi < 4; ++mi) {
#pragma unroll
          for (int r = 0; r < 4; ++r) {
            const int m = mbase + mi * 16 + lg * 4 + r;
            const int bidx = m >> 11, sidx = m & 2047;
            o[(((size_t)bidx * NHEADS + h) * SEQ + sidx) * 64 + dk] =
                f2bf((acc[mi][ni][r] + bv) * sc);
          }
        }
      }
    }
  } else if constexpr (EPI == EPI_WO) {
    // bf16 out = acc + bias + f32 residual
    short* o = (short*)outp;
#pragma unroll
    for (int ni = 0; ni < 4; ++ni) {
      const int n = nbase + ni * 16 + l16;
      const float bv = bias[n];
#pragma unroll
      for (int mi = 0; mi < 4; ++mi)
#pragma unroll
        for (int r = 0; r < 4; ++r) {
          const int m = mbase + mi * 16 + lg * 4 + r;
          const size_t idx = (size_t)m * N + n;
          o[idx] = f2bf(acc[mi][ni][r] + bv + extraF[idx]);
        }
    }
  } else if constexpr (EPI == EPI_FF) {
    // bf16 out = acc + bias + bf16 residual
    short* o = (short*)outp;
#pragma unroll
    for (int ni = 0; ni < 4; ++ni) {
      const int n = nbase + ni * 16 + l16;
      const float bv = bias[n];
#pragma unroll
      for (int mi = 0; mi < 4; ++mi)
#pragma unroll
        for (int r = 0; r < 4; ++r) {
          const int m = mbase + mi * 16 + lg * 4 + r;
          const size_t idx = (size_t)m * N + n;
          o[idx] = f2bf(acc[mi][ni][r] + bv + bf2f(extraB[idx]));
        }
    }
  } else {  // EPI_RELU -> bf16
    short* o = (short*)outp;
#pragma unroll
    for (int ni = 0; ni < 4; ++ni) {
      const int n = nbase + ni * 16 + l16;
      const float bv = bias[n];
#pragma unroll
      for (int mi = 0; mi < 4; ++mi)
#pragma unroll
        for (int r = 0; r < 4; ++r) {
          const int m = mbase + mi * 16 + lg * 4 + r;
          o[(size_t)m * N + n] = f2bf(fmaxf(acc[mi][ni][r] + bv, 0.f));
        }
    }
  }
}

// ---------------- flash attention: swapped QK^T, 32x32x16, ones-MFMA rowsum ----------
__global__ __launch_bounds__(256, 3) void attn_fa2(
    const short* __restrict__ Q,   // [BH,S,64] pre-scaled by 0.125*log2e
    const short* __restrict__ Kb,  // [BH,S,64]
    const short* __restrict__ Vt,  // [BH,64,S]
    const int* __restrict__ mask,  // [B,S]
    short* __restrict__ ctx) {     // [B,S,768]
  __shared__ short KsA[64 * 64], KsB[64 * 64];
  __shared__ short VsA[64 * 64], VsB[64 * 64];
  __shared__ float bc[4][32];
  const int tid = threadIdx.x;
  const int lane = tid & 63, w = tid >> 6;
  const int l31 = lane & 31, hi = lane >> 5;
  const int bh = blockIdx.y, b = bh / NHEADS, h = bh % NHEADS;
  const int q0 = blockIdx.x * 128 + w * 32;

  const short* qp = Q + ((size_t)bh * SEQ + q0 + l31) * 64;
  short8 qf[4];
#pragma unroll
  for (int s = 0; s < 4; ++s) qf[s] = *(const short8*)(qp + s * 16 + hi * 8);

  short8 vones;
#pragma unroll
  for (int i = 0; i < 8; ++i) vones[i] = (short)0x3F80;  // bf16 1.0

  f32x16 o0, o1, o2;
#pragma unroll
  for (int i = 0; i < 16; ++i) { o0[i] = 0.f; o1[i] = 0.f; o2[i] = 0.f; }
  float m = -1e30f;

  auto stage = [&](short* Ksd, short* Vsd, int kv0) {
#pragma unroll
    for (int i = 0; i < 2; ++i) {
      const int c = i * 256 + tid;
      const int row = c >> 3, ch = c & 7;
      const int gc = ch ^ (row & 7);  // pre-swizzled source, linear LDS dest
      gll16(Kb + ((size_t)bh * SEQ + kv0 + row) * 64 + gc * 8,
            (char*)Ksd + (i * 256 + w * 64) * 16);
      gll16(Vt + ((size_t)bh * 64 + row) * SEQ + kv0 + gc * 8,
            (char*)Vsd + (i * 256 + w * 64) * 16);
    }
  };

  stage(KsA, VsA, 0);
  __syncthreads();

  for (int t = 0; t < SEQ / 64; ++t) {
    const short* Ksc = (t & 1) ? KsB : KsA;
    const short* Vsc = (t & 1) ? VsB : VsA;

    // ---- S^T = K Q ----
    f32x16 s0, s1;
#pragma unroll
    for (int i = 0; i < 16; ++i) { s0[i] = 0.f; s1[i] = 0.f; }
#pragma unroll
    for (int slot = 0; slot < 4; ++slot) {
      const int ch0 = (slot * 2 + hi) ^ (l31 & 7);
      short8 a0 = *(const short8*)((const char*)Ksc + l31 * 128 + ch0 * 16);
      s0 = __builtin_amdgcn_mfma_f32_32x32x16_bf16(a0, qf[slot], s0, 0, 0, 0);
      short8 a1 = *(const short8*)((const char*)Ksc + (32 + l31) * 128 + ch0 * 16);
      s1 = __builtin_amdgcn_mfma_f32_32x32x16_bf16(a1, qf[slot], s1, 0, 0, 0);
    }

    // stage next tile AFTER current K-reads: lands during softmax (no LDS traffic)
    if (t + 1 < SEQ / 64)
      stage((t & 1) ? KsA : KsB, (t & 1) ? VsA : VsB, (t + 1) * 64);

    // ---- mask (rare path) ----
    const int mv = mask[(size_t)b * SEQ + t * 64 + lane];
    if (__any(mv == 0)) {
#pragma unroll
      for (int r = 0; r < 16; ++r) {
        const int cr = (r & 3) + 8 * (r >> 2) + 4 * hi;
        if (__shfl(mv, cr) == 0) s0[r] = -1e9f;
        if (__shfl(mv, 32 + cr) == 0) s1[r] = -1e9f;
      }
    }

    // ---- online softmax (log2 domain), max3-shaped reduce ----
    float pmax = fmaxf(s0[0], s0[1]);
#pragma unroll
    for (int r = 2; r < 16; r += 2) pmax = fmaxf(pmax, fmaxf(s0[r], s0[r + 1]));
#pragma unroll
    for (int r = 0; r < 16; r += 2) pmax = fmaxf(pmax, fmaxf(s1[r], s1[r + 1]));
    pmax = fmaxf(pmax, __shfl_xor(pmax, 32));
    if (!__all(pmax - m <= 11.0f)) {  // defer-max
      const float mn = fmaxf(m, pmax);
      const float corr = exp2f(m - mn);
      if (lane < 32) bc[w][l31] = corr;
#pragma unroll
      for (int r = 0; r < 16; ++r) {
        const float cf = bc[w][(r & 3) + 8 * (r >> 2) + 4 * hi];
        o0[r] *= cf;
        o1[r] *= cf;
        o2[r] *= cf;
      }
      m = mn;
    }
#pragma unroll
    for (int r = 0; r < 16; ++r) {
      s0[r] = exp2f(s0[r] - m);
      s1[r] = exp2f(s1[r] - m);
    }

    // ---- P -> bf16 A-frags + PV (+ ones-MFMA rowsum into o2) ----
#pragma unroll
    for (int c = 0; c < 2; ++c) {
      const f32x16 sc = c ? s1 : s0;
#pragma unroll
      for (int ks = 0; ks < 2; ++ks) {
        const int rb = ks * 8;
        int x0_ = cvtpk(sc[rb + 0], sc[rb + 1]);
        int y0_ = cvtpk(sc[rb + 4], sc[rb + 5]);
        int x1_ = cvtpk(sc[rb + 2], sc[rb + 3]);
        int y1_ = cvtpk(sc[rb + 6], sc[rb + 7]);
        int4v pw;
#if __has_builtin(__builtin_amdgcn_permlane32_swap)
        int2v r0 = __builtin_amdgcn_permlane32_swap(x0_, y0_, false, false);
        int2v r1 = __builtin_amdgcn_permlane32_swap(x1_, y1_, false, false);
        pw[0] = r0[0]; pw[1] = r1[0]; pw[2] = r0[1]; pw[3] = r1[1];
#else
        const int ys0 = __shfl_xor(y0_, 32);
        const int xs0 = __shfl_xor(x0_, 32);
        const int ys1 = __shfl_xor(y1_, 32);
        const int xs1 = __shfl_xor(x1_, 32);
        pw[0] = hi ? ys0 : x0_;
        pw[1] = hi ? ys1 : x1_;
        pw[2] = hi ? y0_ : xs0;
        pw[3] = hi ? y1_ : xs1;
#endif
        const short8 pa = __builtin_bit_cast(short8, pw);
        const int vslot = c * 2 + ks;
        {
          const int vch = (vslot * 2 + hi) ^ (l31 & 7);
          short8 vb0 = *(const short8*)((const char*)Vsc + l31 * 128 + vch * 16);
          o0 = __builtin_amdgcn_mfma_f32_32x32x16_bf16(pa, vb0, o0, 0, 0, 0);
          short8 vb1 = *(const short8*)((const char*)Vsc + (32 + l31) * 128 + vch * 16);
          o1 = __builtin_amdgcn_mfma_f32_32x32x16_bf16(pa, vb1, o1, 0, 0, 0);
        }
        o2 = __builtin_amdgcn_mfma_f32_32x32x16_bf16(pa, vones, o2, 0, 0, 0);
      }
    }
    __syncthreads();
  }

  // ---- epilogue: 1/l directly from o2 (all lanes hold the rowsum) ----
#pragma unroll
  for (int r = 0; r < 16; ++r) {
    const int q = (r & 3) + 8 * (r >> 2) + 4 * hi;
    const float inv = 1.f / o2[r];
    short* cp = ctx + ((size_t)b * SEQ + q0 + q) * D_MODEL + h * 64;
    cp[l31] = f2bf(o0[r] * inv);
    cp[32 + l31] = f2bf(o1[r] * inv);
  }
}

// ---------------- LayerNorm: one wave per row, bf16 in, bf16/f32 out ----------------
template <int OUT_F32>
__global__ __launch_bounds__(256) void ln_w(const short* __restrict__ y,
                                            const float* __restrict__ gw,
                                            const float* __restrict__ bw,
                                            float* __restrict__ of,
                                            short* __restrict__ ob) {
  const int lane = threadIdx.x & 63, w = threadIdx.x >> 6;
  const int row = blockIdx.x * 4 + w;
  const short* yr = y + (size_t)row * D_MODEL;
  short8 v8 = *(const short8*)(yr + lane * 8);
  ushort4v v4 = *(const ushort4v*)(yr + 512 + lane * 4);
  float f[12];
#pragma unroll
  for (int j = 0; j < 8; ++j) f[j] = bf2f(v8[j]);
#pragma unroll
  for (int j = 0; j < 4; ++j) f[8 + j] = bf2f((short)v4[j]);
  float s = 0.f, q = 0.f;
#pragma unroll
  for (int j = 0; j < 12; ++j) { s += f[j]; q += f[j] * f[j]; }
#pragma unroll
  for (int mm = 1; mm < 64; mm <<= 1) {
    s += __shfl_xor(s, mm);
    q += __shfl_xor(q, mm);
  }
  const float mu = s * (1.f / D_MODEL);
  const float rs = rsqrtf(q * (1.f / D_MODEL) - mu * mu + 1e-5f);
  float4v g0 = *(const float4v*)(gw + lane * 8);
  float4v g1 = *(const float4v*)(gw + lane * 8 + 4);
  float4v g2 = *(const float4v*)(gw + 512 + lane * 4);
  float4v b0 = *(const float4v*)(bw + lane * 8);
  float4v b1 = *(const float4v*)(bw + lane * 8 + 4);
  float4v b2 = *(const float4v*)(bw + 512 + lane * 4);
  float o[12];
#pragma unroll
  for (int j = 0; j < 4; ++j) o[j] = (f[j] - mu) * rs * g0[j] + b0[j];
#pragma unroll
  for (int j = 0; j < 4; ++j) o[4 + j] = (f[4 + j] - mu) * rs * g1[j] + b1[j];
#pragma unroll
  for (int j = 0; j < 4; ++j) o[8 + j] = (f[8 + j] - mu) * rs * g2[j] + b2[j];
  if constexpr (OUT_F32) {
    float* orow = of + (size_t)row * D_MODEL;
    float4v t0, t1, t2;
#pragma unroll
    for (int j = 0; j < 4; ++j) { t0[j] = o[j]; t1[j] = o[4 + j]; t2[j] = o[8 + j]; }
    *(float4v*)(orow + lane * 8) = t0;
    *(float4v*)(orow + lane * 8 + 4) = t1;
    *(float4v*)(orow + 512 + lane * 4) = t2;
  } else {
    short* orow = ob + (size_t)row * D_MODEL;
    ushort4v t0, t1, t2;
#pragma unroll
    for (int j = 0; j < 4; ++j) {
      t0[j] = (unsigned short)f2bf(o[j]);
      t1[j] = (unsigned short)f2bf(o[4 + j]);
      t2[j] = (unsigned short)f2bf(o[8 + j]);
    }
    *(ushort4v*)(orow + lane * 8) = t0;
    *(ushort4v*)(orow + lane * 8 + 4) = t1;
    *(ushort4v*)(orow + 512 + lane * 4) = t2;
  }
}

// ---------------- launch ----------------
extern "C" void kernel_launch(void* const* d_in, const int* in_sizes, int n_in,
                              void* d_out, int out_size, void* d_ws, size_t ws_size,
                              hipStream_t stream) {
  const float* emb = (const float*)d_in[0];
  const int* mask = (const int*)d_in[1];
  const float* Wq = (const float*)d_in[2];
  const float* bq = (const float*)d_in[3];
  const float* Wk = (const float*)d_in[4];
  const float* bk = (const float*)d_in[5];
  const float* Wv = (const float*)d_in[6];
  const float* bv = (const float*)d_in[7];
  const float* Wo = (const float*)d_in[8];
  const float* bo = (const float*)d_in[9];
  const float* W1 = (const float*)d_in[10];
  const float* b1 = (const float*)d_in[11];
  const float* W2 = (const float*)d_in[12];
  const float* b2 = (const float*)d_in[13];
  const float* lng = (const float*)d_in[14];
  const float* lnb = (const float*)d_in[15];

  char* ws = (char*)d_ws;
  size_t off = 0;
  auto alloc = [&](size_t bytes) -> char* {
    char* p = ws + off;
    off = (off + bytes + 255) & ~(size_t)255;
    return p;
  };
  const size_t DD = (size_t)D_MODEL * D_MODEL;
  const size_t DF = (size_t)D_MODEL * FF_DIM;
  const size_t TD = (size_t)NTOK * D_MODEL;
  const size_t TF = (size_t)NTOK * FF_DIM;

  short* wqkvt = (short*)alloc(3 * DD * 2);
  short* wot = (short*)alloc(DD * 2);
  short* w1t = (short*)alloc(DF * 2);
  short* w2t = (short*)alloc(DF * 2);
  float* bqkv = (float*)alloc(2304 * 4);
  short* x0 = (short*)alloc(TD * 2);     // emb bf16; reused as ctx after QKV
  short* qkv = (short*)alloc(3 * TD * 2);
  short* aresb = (short*)alloc(TD * 2);
  short* xbf = (short*)alloc(TD * 2);
  short* hbf = (short*)alloc(TF * 2);
  short* ffresb = (short*)alloc(TD * 2);
  short* qb = qkv;
  short* kb = qkv + TD;
  short* vtb = qkv + 2 * TD;
  short* ctx = x0;

  prep<<<dim3(1729 + (int)(TD / 1024)), 256, 0, stream>>>(
      Wq, Wk, Wv, Wo, W1, W2, bq, bk, bv, emb, wqkvt, wot, w1t, w2t, bqkv, x0);
  gemm_bt<EPI_QKV><<<dim3(18, 64), 256, 0, stream>>>(
      x0, wqkvt, bqkv, nullptr, nullptr, qkv, NTOK, 3 * D_MODEL, D_MODEL);
  attn_fa2<<<dim3(16, BATCH * NHEADS), 256, 0, stream>>>(qb, kb, vtb, mask, ctx);
  gemm_bt<EPI_WO><<<dim3(6, 64), 256, 0, stream>>>(
      ctx, wot, bo, emb, nullptr, aresb, NTOK, D_MODEL, D_MODEL);
  ln_w<0><<<dim3(NTOK / 4), 256, 0, stream>>>(aresb, lng, lnb, nullptr, xbf);
  gemm_bt<EPI_RELU><<<dim3(24, 64), 256, 0, stream>>>(
      xbf, w1t, b1, nullptr, nullptr, hbf, NTOK, FF_DIM, D_MODEL);
  gemm_bt<EPI_FF><<<dim3(6, 64), 256, 0, stream>>>(
      hbf, w2t, b2, nullptr, xbf, ffresb, NTOK, D_MODEL, FF_DIM);
  ln_w<1><<<dim3(NTOK / 4), 256, 0, stream>>>(ffresb, lng, lnb, (float*)d_out, nullptr);
}